// Round 3
// baseline (68.671 us; speedup 1.0000x reference)
//
#include <hip/hip_runtime.h>
#include <math.h>

#define NDET 128
#define NT   1024
#define NF   513     // NT/2 + 1
#define NB   4
#define NXI  256
#define NYI  256

// 2*pi/(128*0.0003)  -- kx step
#define KX_STEP 163.62462f
// 2*pi/(1024*2.5e-8*1540)  -- (omega/c) step per rfft bin
#define OC_STEP 159.37463f
#define DY_F 1.0e-4f
#define DX_F 1.5e-4f

__device__ __forceinline__ void bfly(float2& a, float2& b, float cw, float sw) {
    float tr = b.x * cw - b.y * sw;
    float ti = b.x * sw + b.y * cw;
    b.x = a.x - tr; b.y = a.y - ti;
    a.x += tr;      a.y += ti;
}

// Stage 1: 128 blocks, each reduces 4096 contiguous floats (float4 loads).
// part[0..127] = sum, part[128..255] = sumsq.  b = blk>>5.
__global__ void k_stats1(const float* __restrict__ sino, float* __restrict__ part) {
    __shared__ float s1[256], s2[256];
    int tid = threadIdx.x;
    int blk = blockIdx.x;
    const float4* p = (const float4*)sino + (size_t)blk * 1024;
    float s = 0.f, q = 0.f;
#pragma unroll
    for (int i = 0; i < 4; ++i) {
        float4 v = p[tid + i * 256];
        s += v.x + v.y + v.z + v.w;
        q += v.x * v.x + v.y * v.y + v.z * v.z + v.w * v.w;
    }
    s1[tid] = s; s2[tid] = q; __syncthreads();
    for (int off = 128; off > 0; off >>= 1) {
        if (tid < off) { s1[tid] += s1[tid + off]; s2[tid] += s2[tid + off]; }
        __syncthreads();
    }
    if (tid == 0) { part[blk] = s1[0]; part[128 + blk] = s2[0]; }
}

// One block per (b,d) row: fold stats partials, normalize, window,
// 1024-pt complex FFT via LDS twiddle table, keep f=0..512.
__global__ void k_fft_time(const float* __restrict__ sino, const float* __restrict__ tw,
                           const float* __restrict__ apod, const float* __restrict__ part,
                           float2* __restrict__ spec) {
    __shared__ float2 X[1024];
    __shared__ float2 W[512];
    __shared__ float2 statS;   // (mean, istd)
    int tid = threadIdx.x;
    int row = blockIdx.x;            // b*128 + d
    int b = row >> 7, d = row & 127;
    // fold per-b stats from partials (lanes 0..31 of wave 0)
    if (tid < 32) {
        float s = part[b * 32 + tid];
        float q = part[128 + b * 32 + tid];
        for (int off = 16; off > 0; off >>= 1) {
            s += __shfl_down(s, off);
            q += __shfl_down(q, off);
        }
        if (tid == 0) {
            float n = 131072.0f;
            float mean = s / n;
            float var = q / n - mean * mean;
            statS = make_float2(mean, 1.0f / sqrtf(var + 1.1920929e-7f));
        }
    }
    // twiddle table W[j] = e^{-2*pi*i*j/1024}
    for (int j = tid; j < 512; j += 256) {
        float sw, cw; __sincosf(-6.28318530718f * (float)j * (1.0f / 1024.0f), &sw, &cw);
        W[j] = make_float2(cw, sw);
    }
    float ap = apod[d];
    const float4* p4 = (const float4*)(sino + (size_t)row * NT);
    const float4* w4 = (const float4*)tw;
    float4 v4 = p4[tid];
    float4 t4 = w4[tid];
    __syncthreads();
    float mean = statS.x, istd = statS.y;
    int t0 = tid * 4;
    X[__brev((unsigned)(t0 + 0)) >> 22] = make_float2((v4.x - mean) * istd * t4.x * ap, 0.f);
    X[__brev((unsigned)(t0 + 1)) >> 22] = make_float2((v4.y - mean) * istd * t4.y * ap, 0.f);
    X[__brev((unsigned)(t0 + 2)) >> 22] = make_float2((v4.z - mean) * istd * t4.z * ap, 0.f);
    X[__brev((unsigned)(t0 + 3)) >> 22] = make_float2((v4.w - mean) * istd * t4.w * ap, 0.f);
    __syncthreads();
    for (int s = 1; s <= 10; ++s) {
        int half = 1 << (s - 1);
        int tsh = 10 - s;
        for (int j = tid; j < 512; j += 256) {
            int grp = j >> (s - 1);
            int pos = j & (half - 1);
            int i1 = (grp << s) + pos;
            int i2 = i1 + half;
            float2 w = W[pos << tsh];
            bfly(X[i1], X[i2], w.x, w.y);
        }
        __syncthreads();
    }
    float2* out = spec + (size_t)row * NF;
    for (int f = tid; f < NF; f += 256) out[f] = X[f];
}

// 128-pt FFT along detector axis for 8 freq bins per block; apply prop_mask*freq_weight.
__global__ void k_fft_det(const float2* __restrict__ spec, const float* __restrict__ pm,
                          const float* __restrict__ fw, float2* __restrict__ wskf) {
    __shared__ float2 Xs[8][128];
    __shared__ float2 Wd[64];
    int tid = threadIdx.x;
    int b  = blockIdx.x / 65;
    int f0 = (blockIdx.x % 65) * 8;
    if (tid < 64) {
        float sw, cw; __sincosf(-6.28318530718f * (float)tid * (1.0f / 128.0f), &sw, &cw);
        Wd[tid] = make_float2(cw, sw);
    }
    for (int l = tid; l < 1024; l += 256) {
        int j = l & 7, d = l >> 3;
        int f = f0 + j;
        float2 v = make_float2(0.f, 0.f);
        if (f < NF) v = spec[((size_t)(b * NDET + d)) * NF + f];
        Xs[j][__brev((unsigned)d) >> 25] = v;
    }
    __syncthreads();
    for (int s = 1; s <= 7; ++s) {
        int half = 1 << (s - 1);
        int tsh = 7 - s;
        for (int l = tid; l < 512; l += 256) {
            int r = l >> 6, q = l & 63;
            int grp = q >> (s - 1), pos = q & (half - 1);
            int i1 = (grp << s) + pos, i2 = i1 + half;
            float2 w = Wd[pos << tsh];
            bfly(Xs[r][i1], Xs[r][i2], w.x, w.y);
        }
        __syncthreads();
    }
    for (int l = tid; l < 1024; l += 256) {
        int j = l & 7, k = l >> 3;
        int f = f0 + j;
        if (f < NF) {
            float mw = pm[k * NF + f] * fw[f];
            float2 v = Xs[j][k];
            wskf[((size_t)(b * NDET + k)) * NF + f] = make_float2(v.x * mw, v.y * mw);
        }
    }
}

// tmp[b,y,k] partials over f-chunks; phase_y recomputed from kz on the fly.
// k-PAIRED: block = (p = |kk| in 0..64) x (c = f-chunk 0..3); kz/sincos shared
// between k=p and k=128-p. 512 threads = 2 f-subchunks x 256 y.
// tmpP layout: [c][b][k][y]
__global__ __launch_bounds__(512) void k_prop(const float2* __restrict__ wskf,
                                              float2* __restrict__ tmpP) {
    __shared__ float  kzs[129];
    __shared__ float2 skA[4][129];
    __shared__ float2 skB[4][129];
    __shared__ float  red[16][256];
    int tid = threadIdx.x;
    int y = tid & 255;
    int h = tid >> 8;                 // f-subchunk
    int p = blockIdx.x >> 2;          // 0..64
    int c = blockIdx.x & 3;
    int kA = p;
    int kB = (128 - p) & 127;
    bool hasB = (p >= 1 && p <= 63);
    int f_start = c * 128;
    int nf_all = (c == 3) ? 129 : 128;
    float kxv = (float)p * KX_STEP;
    float kx2 = kxv * kxv;
    for (int i = tid; i < nf_all; i += 512) {
        float oc = (float)(f_start + i) * OC_STEP;
        float d2 = oc * oc - kx2;
        kzs[i] = d2 > 0.f ? sqrtf(d2) : 0.f;
    }
#pragma unroll
    for (int bb = 0; bb < NB; ++bb) {
        for (int i = tid; i < nf_all; i += 512) {
            skA[bb][i] = wskf[((size_t)(bb * NDET + kA)) * NF + f_start + i];
            skB[bb][i] = hasB ? wskf[((size_t)(bb * NDET + kB)) * NF + f_start + i]
                              : make_float2(0.f, 0.f);
        }
    }
    __syncthreads();
    int i0 = h * 64;
    int i1 = (h == 0) ? 64 : nf_all;
    float yp = (float)y * DY_F;
    float aAr[4] = {0,0,0,0}, aAi[4] = {0,0,0,0};
    float aBr[4] = {0,0,0,0}, aBi[4] = {0,0,0,0};
    for (int i = i0; i < i1; ++i) {
        float sw, cw; __sincosf(yp * kzs[i], &sw, &cw);
#pragma unroll
        for (int bb = 0; bb < 4; ++bb) {
            float2 vA = skA[bb][i];
            aAr[bb] += vA.x * cw - vA.y * sw;  aAi[bb] += vA.x * sw + vA.y * cw;
            float2 vB = skB[bb][i];
            aBr[bb] += vB.x * cw - vB.y * sw;  aBi[bb] += vB.x * sw + vB.y * cw;
        }
    }
    if (h == 1) {
#pragma unroll
        for (int bb = 0; bb < 4; ++bb) {
            red[bb * 4 + 0][y] = aAr[bb];
            red[bb * 4 + 1][y] = aAi[bb];
            red[bb * 4 + 2][y] = aBr[bb];
            red[bb * 4 + 3][y] = aBi[bb];
        }
    }
    __syncthreads();
    if (h == 0) {
        size_t cb = (size_t)c * NB * NDET;
#pragma unroll
        for (int bb = 0; bb < 4; ++bb) {
            float2 vA = make_float2(aAr[bb] + red[bb * 4 + 0][y],
                                    aAi[bb] + red[bb * 4 + 1][y]);
            tmpP[(cb + bb * NDET + kA) * NYI + y] = vA;
            if (hasB) {
                float2 vB = make_float2(aBr[bb] + red[bb * 4 + 2][y],
                                        aBi[bb] + red[bb * 4 + 3][y]);
                tmpP[(cb + bb * NDET + kB) * NYI + y] = vB;
            }
        }
    }
}

// img[b,y,x] = scale * Re sum_k tmp[b,y,k] * e^{i kx[k] * x * dx}
// Rotation recurrence: 1 sincos per thread, k/-k paired.
__global__ void k_img(const float2* __restrict__ tmpP, float* __restrict__ outp) {
    __shared__ float2 ts[4][128];
    int tid = threadIdx.x;
    int y = blockIdx.x;
    for (int l = tid; l < 512; l += 256) {
        int bb = l >> 7, k = l & 127;
        float2 a = make_float2(0.f, 0.f);
        for (int cc = 0; cc < 4; ++cc) {
            float2 v = tmpP[(((size_t)cc * NB + bb) * NDET + k) * NYI + y];
            a.x += v.x; a.y += v.y;
        }
        ts[bb][k] = a;
    }
    __syncthreads();
    float alpha = KX_STEP * (float)tid * DX_F;
    float sa, ca; __sincosf(alpha, &sa, &ca);
    float acc[4];
#pragma unroll
    for (int bb = 0; bb < 4; ++bb) acc[bb] = ts[bb][0].x;   // p=0: cos=1, sin=0
    float c = ca, s = sa;
    for (int p = 1; p <= 63; ++p) {
#pragma unroll
        for (int bb = 0; bb < 4; ++bb) {
            float2 tp = ts[bb][p], tm = ts[bb][128 - p];
            acc[bb] += c * (tp.x + tm.x) - s * (tp.y - tm.y);
        }
        float nc = c * ca - s * sa;
        s = s * ca + c * sa;
        c = nc;
    }
    // p=64 (kk=-64): theta = -64*alpha -> cos=c, sin=-s
#pragma unroll
    for (int bb = 0; bb < 4; ++bb) {
        float2 t64 = ts[bb][64];
        acc[bb] += c * t64.x + s * t64.y;
    }
    const float scale = 1.0f / 131072.0f;   // 1/(n_det * sum(freq_weight)) = 1/(128*1024)
#pragma unroll
    for (int bb = 0; bb < 4; ++bb)
        outp[((size_t)bb * NYI + y) * NXI + tid] = acc[bb] * scale;
}

extern "C" void kernel_launch(void* const* d_in, const int* in_sizes, int n_in,
                              void* d_out, int out_size, void* d_ws, size_t ws_size,
                              hipStream_t stream) {
    const float* sino = (const float*)d_in[0];
    const float* tw   = (const float*)d_in[1];
    const float* apod = (const float*)d_in[2];
    const float* fw   = (const float*)d_in[3];
    const float* pm   = (const float*)d_in[4];
    // d_in[5] (phase_x) and d_in[6] (phase_y) are recomputed on the fly.

    float*  wsf   = (float*)d_ws;
    float*  part  = wsf;                          // 256 floats
    float2* spec  = (float2*)(wsf + 512);         // [4][128][513]
    float2* wskf  = spec + (size_t)NB * NDET * NF;  // [4][128][513]
    float2* tmpP  = wskf + (size_t)NB * NDET * NF;  // [4c][4b][128k][256y]
    float*  outp  = (float*)d_out;

    k_stats1  <<<dim3(128), dim3(256), 0, stream>>>(sino, part);
    k_fft_time<<<dim3(512), dim3(256), 0, stream>>>(sino, tw, apod, part, spec);
    k_fft_det <<<dim3(260), dim3(256), 0, stream>>>(spec, pm, fw, wskf);
    k_prop    <<<dim3(260), dim3(512), 0, stream>>>(wskf, tmpP);
    k_img     <<<dim3(256), dim3(256), 0, stream>>>(tmpP, outp);
}

// Round 4
// 57.966 us; speedup vs baseline: 1.1847x; 1.1847x over previous
//
#include <hip/hip_runtime.h>
#include <math.h>

#define NDET 128
#define NT   1024
#define NF   513     // NT/2 + 1
#define NB   4
#define NXI  256
#define NYI  256
#define NCH  8       // f-chunks in k_prop

// 2*pi/(128*0.0003)  -- kx step
#define KX_STEP 163.62462f
// 2*pi/(1024*2.5e-8*1540)  -- (omega/c) step per rfft bin
#define OC_STEP 159.37463f
#define DY_F 1.0e-4f
#define DX_F 1.5e-4f

__device__ __forceinline__ void bfly(float2& a, float2& b, float cw, float sw) {
    float tr = b.x * cw - b.y * sw;
    float ti = b.x * sw + b.y * cw;
    b.x = a.x - tr; b.y = a.y - ti;
    a.x += tr;      a.y += ti;
}

// Fused launch, 640 blocks:
//   blocks 0..511  : one (b,d) row each -> window*apod, 1024-pt FFT, write spec.
//                    (mean subtraction dropped: f=0 bin is fully masked by prop_mask;
//                     istd is applied as a scalar in k_img.)
//   blocks 512..639: stats partials (sum, sumsq) over 4096 floats each.
__global__ __launch_bounds__(256) void k_fft_time(
        const float* __restrict__ sino, const float* __restrict__ tw,
        const float* __restrict__ apod, float* __restrict__ part,
        float2* __restrict__ spec) {
    __shared__ float2 X[1024];
    int tid = threadIdx.x;
    int blk = blockIdx.x;
    if (blk >= 512) {
        float* s1 = (float*)X;          // reuse LDS
        float* s2 = s1 + 256;
        int sb = blk - 512;
        const float4* p = (const float4*)sino + (size_t)sb * 1024;
        float s = 0.f, q = 0.f;
#pragma unroll
        for (int i = 0; i < 4; ++i) {
            float4 v = p[tid + i * 256];
            s += v.x + v.y + v.z + v.w;
            q += v.x * v.x + v.y * v.y + v.z * v.z + v.w * v.w;
        }
        s1[tid] = s; s2[tid] = q; __syncthreads();
        for (int off = 128; off > 0; off >>= 1) {
            if (tid < off) { s1[tid] += s1[tid + off]; s2[tid] += s2[tid + off]; }
            __syncthreads();
        }
        if (tid == 0) { part[sb] = s1[0]; part[128 + sb] = s2[0]; }
        return;
    }
    int row = blk;                   // b*128 + d
    int d = row & 127;
    float ap = apod[d];
    const float4* p4 = (const float4*)(sino + (size_t)row * NT);
    const float4* w4 = (const float4*)tw;
    float4 v4 = p4[tid];
    float4 t4 = w4[tid];
    int t0 = tid * 4;
    X[__brev((unsigned)(t0 + 0)) >> 22] = make_float2(v4.x * t4.x * ap, 0.f);
    X[__brev((unsigned)(t0 + 1)) >> 22] = make_float2(v4.y * t4.y * ap, 0.f);
    X[__brev((unsigned)(t0 + 2)) >> 22] = make_float2(v4.z * t4.z * ap, 0.f);
    X[__brev((unsigned)(t0 + 3)) >> 22] = make_float2(v4.w * t4.w * ap, 0.f);
    __syncthreads();
    for (int s = 1; s <= 10; ++s) {
        int half = 1 << (s - 1);
        for (int j = tid; j < 512; j += 256) {
            int grp = j >> (s - 1);
            int pos = j & (half - 1);
            int i1 = (grp << s) + pos;
            int i2 = i1 + half;
            float ang = -6.28318530718f * (float)pos / (float)(2 * half);
            float sw, cw; __sincosf(ang, &sw, &cw);
            bfly(X[i1], X[i2], cw, sw);
        }
        __syncthreads();
    }
    float2* out = spec + (size_t)row * NF;
    for (int f = tid; f < NF; f += 256) out[f] = X[f];
}

// 128-pt FFT along detector axis for 8 freq bins per block; apply prop_mask*freq_weight.
__global__ __launch_bounds__(256) void k_fft_det(
        const float2* __restrict__ spec, const float* __restrict__ pm,
        const float* __restrict__ fw, float2* __restrict__ wskf) {
    __shared__ float2 Xs[8][128];
    int tid = threadIdx.x;
    int b  = blockIdx.x / 65;
    int f0 = (blockIdx.x % 65) * 8;
    for (int l = tid; l < 1024; l += 256) {
        int j = l & 7, d = l >> 3;
        int f = f0 + j;
        float2 v = make_float2(0.f, 0.f);
        if (f < NF) v = spec[((size_t)(b * NDET + d)) * NF + f];
        Xs[j][__brev((unsigned)d) >> 25] = v;
    }
    __syncthreads();
    for (int s = 1; s <= 7; ++s) {
        int half = 1 << (s - 1);
        for (int l = tid; l < 512; l += 256) {
            int r = l >> 6, q = l & 63;
            int grp = q >> (s - 1), pos = q & (half - 1);
            int i1 = (grp << s) + pos, i2 = i1 + half;
            float ang = -6.28318530718f * (float)pos / (float)(2 * half);
            float sw, cw; __sincosf(ang, &sw, &cw);
            bfly(Xs[r][i1], Xs[r][i2], cw, sw);
        }
        __syncthreads();
    }
    for (int l = tid; l < 1024; l += 256) {
        int j = l & 7, k = l >> 3;
        int f = f0 + j;
        if (f < NF) {
            float mw = pm[k * NF + f] * fw[f];
            float2 v = Xs[j][k];
            wskf[((size_t)(b * NDET + k)) * NF + f] = make_float2(v.x * mw, v.y * mw);
        }
    }
}

// Propagation partials over f-chunks. k-PAIRED: block = p(0..64) x chunk c(0..7);
// kz (and the sincos) is shared between k=p and k=128-p. 256 threads = y.
// tmpP layout: [c][b][k][y]
__global__ __launch_bounds__(256) void k_prop(const float2* __restrict__ wskf,
                                              float2* __restrict__ tmpP) {
    __shared__ float  kzs[65];
    __shared__ float2 skA[4][65];
    __shared__ float2 skB[4][65];
    int tid = threadIdx.x;
    int p = blockIdx.x >> 3;          // 0..64
    int c = blockIdx.x & 7;           // 0..7
    int f_start = c * 64;
    int nf = (c == 7) ? 65 : 64;
    int kA = p;
    int kB = (128 - p) & 127;
    bool hasB = (p >= 1 && p <= 63);
    float kxv = (float)p * KX_STEP;
    float kx2 = kxv * kxv;
    for (int i = tid; i < nf; i += 256) {
        float oc = (float)(f_start + i) * OC_STEP;
        float d2 = oc * oc - kx2;
        kzs[i] = d2 > 0.f ? sqrtf(d2) : 0.f;
    }
#pragma unroll
    for (int bb = 0; bb < NB; ++bb) {
        for (int i = tid; i < nf; i += 256) {
            skA[bb][i] = wskf[((size_t)(bb * NDET + kA)) * NF + f_start + i];
            skB[bb][i] = hasB ? wskf[((size_t)(bb * NDET + kB)) * NF + f_start + i]
                              : make_float2(0.f, 0.f);
        }
    }
    __syncthreads();
    int y = tid;
    float yp = (float)y * DY_F;
    float aAr[4] = {0,0,0,0}, aAi[4] = {0,0,0,0};
    float aBr[4] = {0,0,0,0}, aBi[4] = {0,0,0,0};
    for (int i = 0; i < nf; ++i) {
        float sw, cw; __sincosf(yp * kzs[i], &sw, &cw);
#pragma unroll
        for (int bb = 0; bb < 4; ++bb) {
            float2 vA = skA[bb][i];
            aAr[bb] += vA.x * cw - vA.y * sw;  aAi[bb] += vA.x * sw + vA.y * cw;
            float2 vB = skB[bb][i];
            aBr[bb] += vB.x * cw - vB.y * sw;  aBi[bb] += vB.x * sw + vB.y * cw;
        }
    }
    size_t cb = (size_t)c * NB * NDET;
#pragma unroll
    for (int bb = 0; bb < 4; ++bb) {
        tmpP[(cb + bb * NDET + kA) * NYI + y] = make_float2(aAr[bb], aAi[bb]);
        if (hasB)
            tmpP[(cb + bb * NDET + kB) * NYI + y] = make_float2(aBr[bb], aBi[bb]);
    }
}

// img[b,y,x] = istd[b]*scale * Re sum_k tmp[b,y,k] * e^{i kx[k] * x * dx}
// block = (y, b-half); rotation recurrence: 1 sincos per thread, k/-k paired.
__global__ __launch_bounds__(256) void k_img(const float2* __restrict__ tmpP,
                                             const float* __restrict__ part,
                                             float* __restrict__ outp) {
    __shared__ float2 ts[2][128];
    __shared__ float sred[4];
    int tid = threadIdx.x;
    int y  = blockIdx.x >> 1;
    int bh = blockIdx.x & 1;          // b in {2bh, 2bh+1}
    // fold stats partials -> sred[g]: g = (local b)*2 + (0:sum,1:sumsq)
    if (tid < 128) {
        int g = tid >> 5, lane = tid & 31;
        int bb = 2 * bh + (g >> 1);
        int which = g & 1;
        float v = part[which * 128 + bb * 32 + lane];
        for (int off = 16; off > 0; off >>= 1) v += __shfl_down(v, off);
        if (lane == 0) sred[g] = v;
    }
    // fold tmpP chunks
    int bl = tid >> 7;                // 0..1
    int k  = tid & 127;
    float2 a = make_float2(0.f, 0.f);
#pragma unroll
    for (int cc = 0; cc < NCH; ++cc) {
        float2 v = tmpP[(((size_t)cc * NB + 2 * bh + bl) * NDET + k) * NYI + y];
        a.x += v.x; a.y += v.y;
    }
    ts[bl][k] = a;
    __syncthreads();
    const float inv_n = 1.0f / 131072.0f;
    float m0 = sred[0] * inv_n;
    float v0 = sred[1] * inv_n - m0 * m0;
    float m1 = sred[2] * inv_n;
    float v1 = sred[3] * inv_n - m1 * m1;
    // scale = istd[b] / (n_det * sum(freq_weight)) = istd[b] / 131072
    float sc0 = inv_n / sqrtf(v0 + 1.1920929e-7f);
    float sc1 = inv_n / sqrtf(v1 + 1.1920929e-7f);
    float alpha = KX_STEP * (float)tid * DX_F;
    float sa, ca; __sincosf(alpha, &sa, &ca);
    float acc0 = ts[0][0].x, acc1 = ts[1][0].x;   // p=0: cos=1, sin=0
    float c = ca, s = sa;
    for (int p = 1; p <= 63; ++p) {
        float2 tp0 = ts[0][p], tm0 = ts[0][128 - p];
        acc0 += c * (tp0.x + tm0.x) - s * (tp0.y - tm0.y);
        float2 tp1 = ts[1][p], tm1 = ts[1][128 - p];
        acc1 += c * (tp1.x + tm1.x) - s * (tp1.y - tm1.y);
        float nc = c * ca - s * sa;
        s = s * ca + c * sa;
        c = nc;
    }
    // p=64 (kk=-64): cos=c, sin=-s
    float2 t640 = ts[0][64], t641 = ts[1][64];
    acc0 += c * t640.x + s * t640.y;
    acc1 += c * t641.x + s * t641.y;
    outp[((size_t)(2 * bh + 0) * NYI + y) * NXI + tid] = acc0 * sc0;
    outp[((size_t)(2 * bh + 1) * NYI + y) * NXI + tid] = acc1 * sc1;
}

extern "C" void kernel_launch(void* const* d_in, const int* in_sizes, int n_in,
                              void* d_out, int out_size, void* d_ws, size_t ws_size,
                              hipStream_t stream) {
    const float* sino = (const float*)d_in[0];
    const float* tw   = (const float*)d_in[1];
    const float* apod = (const float*)d_in[2];
    const float* fw   = (const float*)d_in[3];
    const float* pm   = (const float*)d_in[4];
    // d_in[5] (phase_x) and d_in[6] (phase_y) are recomputed on the fly.

    float*  wsf   = (float*)d_ws;
    float*  part  = wsf;                          // 256 floats
    float2* spec  = (float2*)(wsf + 512);         // [4][128][513]
    float2* wskf  = spec + (size_t)NB * NDET * NF;  // [4][128][513]
    float2* tmpP  = wskf + (size_t)NB * NDET * NF;  // [8c][4b][128k][256y]
    float*  outp  = (float*)d_out;

    k_fft_time<<<dim3(640), dim3(256), 0, stream>>>(sino, tw, apod, part, spec);
    k_fft_det <<<dim3(260), dim3(256), 0, stream>>>(spec, pm, fw, wskf);
    k_prop    <<<dim3(520), dim3(256), 0, stream>>>(wskf, tmpP);
    k_img     <<<dim3(512), dim3(256), 0, stream>>>(tmpP, part, outp);
}

// Round 5
// 53.452 us; speedup vs baseline: 1.2847x; 1.0845x over previous
//
#include <hip/hip_runtime.h>
#include <math.h>

#define NDET 128
#define NT   1024
#define NF   513     // NT/2 + 1
#define NB   4
#define NXI  256
#define NYI  256
#define NCH  8       // f-chunks in k_prop

// 2*pi/(128*0.0003)  -- kx step
#define KX_STEP 163.62462f
// 2*pi/(1024*2.5e-8*1540)  -- (omega/c) step per rfft bin
#define OC_STEP 159.37463f
#define DY_F 1.0e-4f
#define DX_F 1.5e-4f

__device__ __forceinline__ void bfly(float2& a, float2& b, float cw, float sw) {
    float tr = b.x * cw - b.y * sw;
    float ti = b.x * sw + b.y * cw;
    b.x = a.x - tr; b.y = a.y - ti;
    a.x += tr;      a.y += ti;
}

// padded LDS index: +1 float2 every 16 (breaks pow-2 bank strides)
__device__ __forceinline__ int ax(int i) { return i + (i >> 4); }

// 512 blocks: one (b,d) row each. Raw row stats (shfl reduce -> part[row]),
// window*apod, 1024-pt radix-2 FFT in padded LDS, write f=0..512.
// (mean subtraction dropped: the f=0 bin is fully masked by prop_mask;
//  istd is applied as a per-b scalar in k_img.)
__global__ __launch_bounds__(256) void k_fft_time(
        const float* __restrict__ sino, const float* __restrict__ tw,
        const float* __restrict__ apod, float* __restrict__ part,
        float2* __restrict__ spec) {
    __shared__ float2 X[1088];         // 1024 + 64 pad
    __shared__ float sw4[4], qw4[4];
    int tid = threadIdx.x;
    int row = blockIdx.x;            // b*128 + d
    int d = row & 127;
    float ap = apod[d];
    const float4* p4 = (const float4*)(sino + (size_t)row * NT);
    const float4* w4 = (const float4*)tw;
    float4 v4 = p4[tid];
    float4 t4 = w4[tid];
    // raw stats over this row (pre-window)
    float s = v4.x + v4.y + v4.z + v4.w;
    float q = v4.x * v4.x + v4.y * v4.y + v4.z * v4.z + v4.w * v4.w;
#pragma unroll
    for (int off = 32; off > 0; off >>= 1) {
        s += __shfl_down(s, off);
        q += __shfl_down(q, off);
    }
    if ((tid & 63) == 0) { sw4[tid >> 6] = s; qw4[tid >> 6] = q; }
    int t0 = tid * 4;
    X[ax(__brev((unsigned)(t0 + 0)) >> 22)] = make_float2(v4.x * t4.x * ap, 0.f);
    X[ax(__brev((unsigned)(t0 + 1)) >> 22)] = make_float2(v4.y * t4.y * ap, 0.f);
    X[ax(__brev((unsigned)(t0 + 2)) >> 22)] = make_float2(v4.z * t4.z * ap, 0.f);
    X[ax(__brev((unsigned)(t0 + 3)) >> 22)] = make_float2(v4.w * t4.w * ap, 0.f);
    __syncthreads();
    if (tid == 0) {
        part[row]       = sw4[0] + sw4[1] + sw4[2] + sw4[3];
        part[512 + row] = qw4[0] + qw4[1] + qw4[2] + qw4[3];
    }
    for (int st = 1; st <= 10; ++st) {
        int half = 1 << (st - 1);
        for (int j = tid; j < 512; j += 256) {
            int grp = j >> (st - 1);
            int pos = j & (half - 1);
            int i1 = (grp << st) + pos;
            int i2 = i1 + half;
            float ang = -6.28318530718f * (float)pos / (float)(2 * half);
            float sn, cs; __sincosf(ang, &sn, &cs);
            bfly(X[ax(i1)], X[ax(i2)], cs, sn);
        }
        __syncthreads();
    }
    float2* out = spec + (size_t)row * NF;
    for (int f = tid; f < NF; f += 256) out[f] = X[ax(f)];
}

// 512 blocks = 4b x 128 f-groups of 4 bins (fg=127 also carries Nyquist f=512).
// 128-pt detector FFT per bin; apply prop_mask*freq_weight.
__global__ __launch_bounds__(256) void k_fft_det(
        const float2* __restrict__ spec, const float* __restrict__ pm,
        const float* __restrict__ fw, float2* __restrict__ wskf) {
    __shared__ float2 Xs[5][128];
    int tid = threadIdx.x;
    int b  = blockIdx.x >> 7;
    int fg = blockIdx.x & 127;
    int rows = (fg == 127) ? 5 : 4;
    int f0 = fg * 4;
    for (int l = tid; l < 512; l += 256) {
        int j = l & 3, dd = l >> 2;
        Xs[j][__brev((unsigned)dd) >> 25] = spec[((size_t)(b * NDET + dd)) * NF + f0 + j];
    }
    if (rows == 5 && tid < 128)
        Xs[4][__brev((unsigned)tid) >> 25] = spec[((size_t)(b * NDET + tid)) * NF + 512];
    __syncthreads();
    for (int st = 1; st <= 7; ++st) {
        int half = 1 << (st - 1);
        for (int l = tid; l < rows * 64; l += 256) {
            int r = l >> 6, qq = l & 63;
            int grp = qq >> (st - 1), pos = qq & (half - 1);
            int i1 = (grp << st) + pos, i2 = i1 + half;
            float ang = -6.28318530718f * (float)pos / (float)(2 * half);
            float sn, cs; __sincosf(ang, &sn, &cs);
            bfly(Xs[r][i1], Xs[r][i2], cs, sn);
        }
        __syncthreads();
    }
    for (int l = tid; l < 512; l += 256) {
        int j = l & 3, k = l >> 2;
        float mw = pm[k * NF + f0 + j] * fw[f0 + j];
        float2 v = Xs[j][k];
        wskf[((size_t)(b * NDET + k)) * NF + f0 + j] = make_float2(v.x * mw, v.y * mw);
    }
    if (rows == 5 && tid < 128) {
        int k = tid;
        float mw = pm[k * NF + 512] * fw[512];
        float2 v = Xs[4][k];
        wskf[((size_t)(b * NDET + k)) * NF + 512] = make_float2(v.x * mw, v.y * mw);
    }
}

// 512 blocks = (p 0..63) x (f-chunk c 0..7). Block p pairs kA=p with kB=128-p
// (shared kz & sincos); block p=0 instead carries kB=64 with its own kz/sincos.
// tmpP layout: [c][b][k][y]
__global__ __launch_bounds__(256) void k_prop(const float2* __restrict__ wskf,
                                              float2* __restrict__ tmpP) {
    __shared__ float  kzA[65], kzB[65];
    __shared__ float2 skA[4][65], skB[4][65];
    int tid = threadIdx.x;
    int p = blockIdx.x >> 3;          // 0..63
    int c = blockIdx.x & 7;           // 0..7
    int f_start = c * 64;
    int nf = (c == 7) ? 65 : 64;
    int kA = p;
    int kB = (p == 0) ? 64 : 128 - p;
    float kxA = (float)p * KX_STEP;
    float kxB = (p == 0) ? 64.0f * KX_STEP : kxA;
    float kxA2 = kxA * kxA, kxB2 = kxB * kxB;
    for (int i = tid; i < nf; i += 256) {
        float oc = (float)(f_start + i) * OC_STEP;
        float o2 = oc * oc;
        float dA = o2 - kxA2, dB = o2 - kxB2;
        kzA[i] = dA > 0.f ? sqrtf(dA) : 0.f;
        kzB[i] = dB > 0.f ? sqrtf(dB) : 0.f;
    }
#pragma unroll
    for (int bb = 0; bb < NB; ++bb) {
        for (int i = tid; i < nf; i += 256) {
            skA[bb][i] = wskf[((size_t)(bb * NDET + kA)) * NF + f_start + i];
            skB[bb][i] = wskf[((size_t)(bb * NDET + kB)) * NF + f_start + i];
        }
    }
    __syncthreads();
    int y = tid;
    float yp = (float)y * DY_F;
    float aAr[4] = {0,0,0,0}, aAi[4] = {0,0,0,0};
    float aBr[4] = {0,0,0,0}, aBi[4] = {0,0,0,0};
    bool p0 = (p == 0);
    for (int i = 0; i < nf; ++i) {
        float snA, csA; __sincosf(yp * kzA[i], &snA, &csA);
        float snB, csB;
        if (p0) { __sincosf(yp * kzB[i], &snB, &csB); }
        else    { snB = snA; csB = csA; }
#pragma unroll
        for (int bb = 0; bb < 4; ++bb) {
            float2 vA = skA[bb][i];
            aAr[bb] += vA.x * csA - vA.y * snA;  aAi[bb] += vA.x * snA + vA.y * csA;
            float2 vB = skB[bb][i];
            aBr[bb] += vB.x * csB - vB.y * snB;  aBi[bb] += vB.x * snB + vB.y * csB;
        }
    }
    size_t cb = (size_t)c * NB * NDET;
#pragma unroll
    for (int bb = 0; bb < 4; ++bb) {
        tmpP[(cb + bb * NDET + kA) * NYI + y] = make_float2(aAr[bb], aAi[bb]);
        tmpP[(cb + bb * NDET + kB) * NYI + y] = make_float2(aBr[bb], aBi[bb]);
    }
}

// img[b,y,x] = istd[b]/131072 * Re sum_k tmp[b,y,k] * e^{i kx[k] * x * dx}
// 512 blocks = (y, b-half). Rotation recurrence: 1 sincos/thread, k/-k paired.
__global__ __launch_bounds__(256) void k_img(const float2* __restrict__ tmpP,
                                             const float* __restrict__ part,
                                             float* __restrict__ outp) {
    __shared__ float2 ts[2][128];
    __shared__ float sred[4];
    int tid = threadIdx.x;
    int y  = blockIdx.x >> 1;
    int bh = blockIdx.x & 1;          // b in {2bh, 2bh+1}
    // fold per-row stats partials: g = (local b)*2 + (0:sum,1:sumsq), one wave per g
    {
        int g = tid >> 6, lane = tid & 63;
        int bb = 2 * bh + (g >> 1);
        int which = g & 1;
        float v = part[which * 512 + bb * 128 + lane] +
                  part[which * 512 + bb * 128 + 64 + lane];
#pragma unroll
        for (int off = 32; off > 0; off >>= 1) v += __shfl_down(v, off);
        if (lane == 0) sred[g] = v;
    }
    // fold tmpP chunks
    int bl = tid >> 7;                // 0..1
    int k  = tid & 127;
    float2 a = make_float2(0.f, 0.f);
#pragma unroll
    for (int cc = 0; cc < NCH; ++cc) {
        float2 v = tmpP[(((size_t)cc * NB + 2 * bh + bl) * NDET + k) * NYI + y];
        a.x += v.x; a.y += v.y;
    }
    ts[bl][k] = a;
    __syncthreads();
    const float inv_n = 1.0f / 131072.0f;
    float m0 = sred[0] * inv_n;
    float v0 = sred[1] * inv_n - m0 * m0;
    float m1 = sred[2] * inv_n;
    float v1 = sred[3] * inv_n - m1 * m1;
    // scale = istd[b] / (n_det * sum(freq_weight)) = istd[b] / 131072
    float sc0 = inv_n / sqrtf(v0 + 1.1920929e-7f);
    float sc1 = inv_n / sqrtf(v1 + 1.1920929e-7f);
    float alpha = KX_STEP * (float)tid * DX_F;
    float sa, ca; __sincosf(alpha, &sa, &ca);
    float acc0 = ts[0][0].x, acc1 = ts[1][0].x;   // p=0: cos=1, sin=0
    float c = ca, s = sa;
    for (int p = 1; p <= 63; ++p) {
        float2 tp0 = ts[0][p], tm0 = ts[0][128 - p];
        acc0 += c * (tp0.x + tm0.x) - s * (tp0.y - tm0.y);
        float2 tp1 = ts[1][p], tm1 = ts[1][128 - p];
        acc1 += c * (tp1.x + tm1.x) - s * (tp1.y - tm1.y);
        float nc = c * ca - s * sa;
        s = s * ca + c * sa;
        c = nc;
    }
    // p=64 (kk=-64): cos=c, sin=-s
    float2 t640 = ts[0][64], t641 = ts[1][64];
    acc0 += c * t640.x + s * t640.y;
    acc1 += c * t641.x + s * t641.y;
    outp[((size_t)(2 * bh + 0) * NYI + y) * NXI + tid] = acc0 * sc0;
    outp[((size_t)(2 * bh + 1) * NYI + y) * NXI + tid] = acc1 * sc1;
}

extern "C" void kernel_launch(void* const* d_in, const int* in_sizes, int n_in,
                              void* d_out, int out_size, void* d_ws, size_t ws_size,
                              hipStream_t stream) {
    const float* sino = (const float*)d_in[0];
    const float* tw   = (const float*)d_in[1];
    const float* apod = (const float*)d_in[2];
    const float* pm   = (const float*)d_in[4];
    const float* fw   = (const float*)d_in[3];
    // d_in[5] (phase_x) and d_in[6] (phase_y) are recomputed on the fly.

    float*  wsf   = (float*)d_ws;
    float*  part  = wsf;                          // 1024 floats (512 sum + 512 sumsq)
    float2* spec  = (float2*)(wsf + 1024);        // [4][128][513]
    float2* wskf  = spec + (size_t)NB * NDET * NF;  // [4][128][513]
    float2* tmpP  = wskf + (size_t)NB * NDET * NF;  // [8c][4b][128k][256y]
    float*  outp  = (float*)d_out;

    k_fft_time<<<dim3(512), dim3(256), 0, stream>>>(sino, tw, apod, part, spec);
    k_fft_det <<<dim3(512), dim3(256), 0, stream>>>(spec, pm, fw, wskf);
    k_prop    <<<dim3(512), dim3(256), 0, stream>>>(wskf, tmpP);
    k_img     <<<dim3(512), dim3(256), 0, stream>>>(tmpP, part, outp);
}

// Round 6
// 52.984 us; speedup vs baseline: 1.2961x; 1.0088x over previous
//
#include <hip/hip_runtime.h>
#include <math.h>

#define NDET 128
#define NT   1024
#define NF   513     // NT/2 + 1
#define NB   4
#define NXI  256
#define NYI  256
#define NCH  8       // f-chunks in k_prop

// 2*pi/(128*0.0003)  -- kx step
#define KX_STEP 163.62462f
// 2*pi/(1024*2.5e-8*1540)  -- (omega/c) step per rfft bin
#define OC_STEP 159.37463f
#define DY_F 1.0e-4f
#define DX_F 1.5e-4f

__device__ __forceinline__ void bfly(float2& a, float2& b, float cw, float sw) {
    float tr = b.x * cw - b.y * sw;
    float ti = b.x * sw + b.y * cw;
    b.x = a.x - tr; b.y = a.y - ti;
    a.x += tr;      a.y += ti;
}

// padded LDS index: +1 float2 every 16 (breaks pow-2 bank strides)
__device__ __forceinline__ int ax(int i) { return i + (i >> 4); }

// 512 blocks: one (b,d) row each. Raw row stats (shfl reduce -> part[row]),
// window*apod, 1024-pt radix-2 FFT in padded LDS, write f=0..512.
// (mean subtraction dropped: the f=0 bin is fully masked by prop_mask;
//  istd is applied as a per-b scalar in k_img.)
__global__ __launch_bounds__(256) void k_fft_time(
        const float* __restrict__ sino, const float* __restrict__ tw,
        const float* __restrict__ apod, float* __restrict__ part,
        float2* __restrict__ spec) {
    __shared__ float2 X[1088];         // 1024 + 64 pad
    __shared__ float sw4[4], qw4[4];
    int tid = threadIdx.x;
    int row = blockIdx.x;            // b*128 + d
    int d = row & 127;
    float ap = apod[d];
    const float4* p4 = (const float4*)(sino + (size_t)row * NT);
    const float4* w4 = (const float4*)tw;
    float4 v4 = p4[tid];
    float4 t4 = w4[tid];
    // raw stats over this row (pre-window)
    float s = v4.x + v4.y + v4.z + v4.w;
    float q = v4.x * v4.x + v4.y * v4.y + v4.z * v4.z + v4.w * v4.w;
#pragma unroll
    for (int off = 32; off > 0; off >>= 1) {
        s += __shfl_down(s, off);
        q += __shfl_down(q, off);
    }
    if ((tid & 63) == 0) { sw4[tid >> 6] = s; qw4[tid >> 6] = q; }
    int t0 = tid * 4;
    X[ax(__brev((unsigned)(t0 + 0)) >> 22)] = make_float2(v4.x * t4.x * ap, 0.f);
    X[ax(__brev((unsigned)(t0 + 1)) >> 22)] = make_float2(v4.y * t4.y * ap, 0.f);
    X[ax(__brev((unsigned)(t0 + 2)) >> 22)] = make_float2(v4.z * t4.z * ap, 0.f);
    X[ax(__brev((unsigned)(t0 + 3)) >> 22)] = make_float2(v4.w * t4.w * ap, 0.f);
    __syncthreads();
    if (tid == 0) {
        part[row]       = sw4[0] + sw4[1] + sw4[2] + sw4[3];
        part[512 + row] = qw4[0] + qw4[1] + qw4[2] + qw4[3];
    }
    for (int st = 1; st <= 10; ++st) {
        int half = 1 << (st - 1);
        for (int j = tid; j < 512; j += 256) {
            int grp = j >> (st - 1);
            int pos = j & (half - 1);
            int i1 = (grp << st) + pos;
            int i2 = i1 + half;
            float ang = -6.28318530718f * (float)pos / (float)(2 * half);
            float sn, cs; __sincosf(ang, &sn, &cs);
            bfly(X[ax(i1)], X[ax(i2)], cs, sn);
        }
        __syncthreads();
    }
    float2* out = spec + (size_t)row * NF;
    for (int f = tid; f < NF; f += 256) out[f] = X[ax(f)];
}

// 512 blocks = 4b x 128 f-groups of 4 bins (fg=127 also carries Nyquist f=512).
// 128-pt detector FFT per bin; apply prop_mask*freq_weight.
__global__ __launch_bounds__(256) void k_fft_det(
        const float2* __restrict__ spec, const float* __restrict__ pm,
        const float* __restrict__ fw, float2* __restrict__ wskf) {
    __shared__ float2 Xs[5][128];
    int tid = threadIdx.x;
    int b  = blockIdx.x >> 7;
    int fg = blockIdx.x & 127;
    int rows = (fg == 127) ? 5 : 4;
    int f0 = fg * 4;
    for (int l = tid; l < 512; l += 256) {
        int j = l & 3, dd = l >> 2;
        Xs[j][__brev((unsigned)dd) >> 25] = spec[((size_t)(b * NDET + dd)) * NF + f0 + j];
    }
    if (rows == 5 && tid < 128)
        Xs[4][__brev((unsigned)tid) >> 25] = spec[((size_t)(b * NDET + tid)) * NF + 512];
    __syncthreads();
    for (int st = 1; st <= 7; ++st) {
        int half = 1 << (st - 1);
        for (int l = tid; l < rows * 64; l += 256) {
            int r = l >> 6, qq = l & 63;
            int grp = qq >> (st - 1), pos = qq & (half - 1);
            int i1 = (grp << st) + pos, i2 = i1 + half;
            float ang = -6.28318530718f * (float)pos / (float)(2 * half);
            float sn, cs; __sincosf(ang, &sn, &cs);
            bfly(Xs[r][i1], Xs[r][i2], cs, sn);
        }
        __syncthreads();
    }
    for (int l = tid; l < 512; l += 256) {
        int j = l & 3, k = l >> 2;
        float mw = pm[k * NF + f0 + j] * fw[f0 + j];
        float2 v = Xs[j][k];
        wskf[((size_t)(b * NDET + k)) * NF + f0 + j] = make_float2(v.x * mw, v.y * mw);
    }
    if (rows == 5 && tid < 128) {
        int k = tid;
        float mw = pm[k * NF + 512] * fw[512];
        float2 v = Xs[4][k];
        wskf[((size_t)(b * NDET + k)) * NF + 512] = make_float2(v.x * mw, v.y * mw);
    }
}

// 512 blocks = (p 0..63) x (f-chunk c 0..7). Block p pairs kA=p with kB=128-p
// (shared kz & sincos); block p=0 instead carries kB=64 with its own kz/sincos.
// sk packed per-b as float4 (A.re,A.im,B.re,B.im) -> 4 ds_read_b128 + 1 b64/iter.
// tmpP layout: [c][b][k][y]
__global__ __launch_bounds__(256) void k_prop(const float2* __restrict__ wskf,
                                              float2* __restrict__ tmpP) {
    __shared__ float2 kz2[65];
    __shared__ float4 sk4[4][65];
    int tid = threadIdx.x;
    int p = blockIdx.x >> 3;          // 0..63
    int c = blockIdx.x & 7;           // 0..7
    int f_start = c * 64;
    int nf = (c == 7) ? 65 : 64;
    int kA = p;
    int kB = (p == 0) ? 64 : 128 - p;
    float kxA = (float)p * KX_STEP;
    float kxB = (p == 0) ? 64.0f * KX_STEP : kxA;
    float kxA2 = kxA * kxA, kxB2 = kxB * kxB;
    for (int i = tid; i < nf; i += 256) {
        float oc = (float)(f_start + i) * OC_STEP;
        float o2 = oc * oc;
        float dA = o2 - kxA2, dB = o2 - kxB2;
        kz2[i] = make_float2(dA > 0.f ? sqrtf(dA) : 0.f,
                             dB > 0.f ? sqrtf(dB) : 0.f);
    }
    // stage (coalesced): lane = (bb = tid>>6, i = tid&63)
    {
        int bb = tid >> 6, i = tid & 63;
        float2 vA = wskf[((size_t)(bb * NDET + kA)) * NF + f_start + i];
        float2 vB = wskf[((size_t)(bb * NDET + kB)) * NF + f_start + i];
        sk4[bb][i] = make_float4(vA.x, vA.y, vB.x, vB.y);
        if (c == 7 && tid < 4) {
            float2 wA = wskf[((size_t)(tid * NDET + kA)) * NF + 512];
            float2 wB = wskf[((size_t)(tid * NDET + kB)) * NF + 512];
            sk4[tid][64] = make_float4(wA.x, wA.y, wB.x, wB.y);
        }
    }
    __syncthreads();
    float yp = (float)tid * DY_F;
    float aAr[4] = {0,0,0,0}, aAi[4] = {0,0,0,0};
    float aBr[4] = {0,0,0,0}, aBi[4] = {0,0,0,0};
    bool p0 = (p == 0);
#pragma unroll 4
    for (int i = 0; i < nf; ++i) {
        float2 kz = kz2[i];
        float snA, csA; __sincosf(yp * kz.x, &snA, &csA);
        float snB, csB;
        if (p0) { __sincosf(yp * kz.y, &snB, &csB); }
        else    { snB = snA; csB = csA; }
#pragma unroll
        for (int bb = 0; bb < 4; ++bb) {
            float4 v = sk4[bb][i];
            aAr[bb] += v.x * csA - v.y * snA;  aAi[bb] += v.x * snA + v.y * csA;
            aBr[bb] += v.z * csB - v.w * snB;  aBi[bb] += v.z * snB + v.w * csB;
        }
    }
    int y = tid;
    size_t cb = (size_t)c * NB * NDET;
#pragma unroll
    for (int bb = 0; bb < 4; ++bb) {
        tmpP[(cb + bb * NDET + kA) * NYI + y] = make_float2(aAr[bb], aAi[bb]);
        tmpP[(cb + bb * NDET + kB) * NYI + y] = make_float2(aBr[bb], aBi[bb]);
    }
}

// img[b,y,x] = istd[b]/131072 * Re sum_k tmp[b,y,k] * e^{i kx[k] * x * dx}
// 512 blocks = (y, b-half). ts packed float4 (b0.re,b0.im,b1.re,b1.im) per k;
// rotation recurrence: 1 sincos/thread, k/-k paired, 2 ds_read_b128/iter.
__global__ __launch_bounds__(256) void k_img(const float2* __restrict__ tmpP,
                                             const float* __restrict__ part,
                                             float* __restrict__ outp) {
    __shared__ float4 ts4[128];
    __shared__ float sred[4];
    int tid = threadIdx.x;
    int y  = blockIdx.x >> 1;
    int bh = blockIdx.x & 1;          // b in {2bh, 2bh+1}
    // fold per-row stats partials: g = (local b)*2 + (0:sum,1:sumsq), one wave per g
    {
        int g = tid >> 6, lane = tid & 63;
        int bb = 2 * bh + (g >> 1);
        int which = g & 1;
        float v = part[which * 512 + bb * 128 + lane] +
                  part[which * 512 + bb * 128 + 64 + lane];
#pragma unroll
        for (int off = 32; off > 0; off >>= 1) v += __shfl_down(v, off);
        if (lane == 0) sred[g] = v;
    }
    // fold tmpP chunks
    int bl = tid >> 7;                // 0..1
    int k  = tid & 127;
    float2 a = make_float2(0.f, 0.f);
#pragma unroll
    for (int cc = 0; cc < NCH; ++cc) {
        float2 v = tmpP[(((size_t)cc * NB + 2 * bh + bl) * NDET + k) * NYI + y];
        a.x += v.x; a.y += v.y;
    }
    {
        float* tf = (float*)&ts4[k];
        tf[2 * bl + 0] = a.x;
        tf[2 * bl + 1] = a.y;
    }
    __syncthreads();
    const float inv_n = 1.0f / 131072.0f;
    float m0 = sred[0] * inv_n;
    float v0 = sred[1] * inv_n - m0 * m0;
    float m1 = sred[2] * inv_n;
    float v1 = sred[3] * inv_n - m1 * m1;
    // scale = istd[b] / (n_det * sum(freq_weight)) = istd[b] / 131072
    float sc0 = inv_n / sqrtf(v0 + 1.1920929e-7f);
    float sc1 = inv_n / sqrtf(v1 + 1.1920929e-7f);
    float alpha = KX_STEP * (float)tid * DX_F;
    float sa, ca; __sincosf(alpha, &sa, &ca);
    float4 t0v = ts4[0];
    float acc0 = t0v.x, acc1 = t0v.z;             // p=0: cos=1, sin=0
    float c = ca, s = sa;
    for (int p = 1; p <= 63; ++p) {
        float4 tp = ts4[p], tm = ts4[128 - p];
        acc0 += c * (tp.x + tm.x) - s * (tp.y - tm.y);
        acc1 += c * (tp.z + tm.z) - s * (tp.w - tm.w);
        float nc = c * ca - s * sa;
        s = s * ca + c * sa;
        c = nc;
    }
    // p=64 (kk=-64): cos=c, sin=-s
    float4 t64 = ts4[64];
    acc0 += c * t64.x + s * t64.y;
    acc1 += c * t64.z + s * t64.w;
    outp[((size_t)(2 * bh + 0) * NYI + y) * NXI + tid] = acc0 * sc0;
    outp[((size_t)(2 * bh + 1) * NYI + y) * NXI + tid] = acc1 * sc1;
}

extern "C" void kernel_launch(void* const* d_in, const int* in_sizes, int n_in,
                              void* d_out, int out_size, void* d_ws, size_t ws_size,
                              hipStream_t stream) {
    const float* sino = (const float*)d_in[0];
    const float* tw   = (const float*)d_in[1];
    const float* apod = (const float*)d_in[2];
    const float* fw   = (const float*)d_in[3];
    const float* pm   = (const float*)d_in[4];
    // d_in[5] (phase_x) and d_in[6] (phase_y) are recomputed on the fly.

    float*  wsf   = (float*)d_ws;
    float*  part  = wsf;                          // 1024 floats (512 sum + 512 sumsq)
    float2* spec  = (float2*)(wsf + 1024);        // [4][128][513]
    float2* wskf  = spec + (size_t)NB * NDET * NF;  // [4][128][513]
    float2* tmpP  = wskf + (size_t)NB * NDET * NF;  // [8c][4b][128k][256y]
    float*  outp  = (float*)d_out;

    k_fft_time<<<dim3(512), dim3(256), 0, stream>>>(sino, tw, apod, part, spec);
    k_fft_det <<<dim3(512), dim3(256), 0, stream>>>(spec, pm, fw, wskf);
    k_prop    <<<dim3(512), dim3(256), 0, stream>>>(wskf, tmpP);
    k_img     <<<dim3(512), dim3(256), 0, stream>>>(tmpP, part, outp);
}

// Round 7
// 52.620 us; speedup vs baseline: 1.3050x; 1.0069x over previous
//
#include <hip/hip_runtime.h>
#include <math.h>

#define NDET 128
#define NT   1024
#define NF   513     // NT/2 + 1
#define NB   4
#define NXI  256
#define NYI  256
#define NCH  8       // f-chunks in k_prop

// 2*pi/(128*0.0003)  -- kx step
#define KX_STEP 163.62462f
// 2*pi/(1024*2.5e-8*1540)  -- (omega/c) step per rfft bin
#define OC_STEP 159.37463f
#define DY_F 1.0e-4f
#define DX_F 1.5e-4f

__device__ __forceinline__ void bfly(float2& a, float2& b, float cw, float sw) {
    float tr = b.x * cw - b.y * sw;
    float ti = b.x * sw + b.y * cw;
    b.x = a.x - tr; b.y = a.y - ti;
    a.x += tr;      a.y += ti;
}

// padded LDS index: +1 float2 every 16 (breaks pow-2 bank strides)
__device__ __forceinline__ int ax(int i) { return i + (i >> 4); }

// 256 blocks: rows 2*blk and 2*blk+1 (same b) packed into ONE 1024-pt complex
// FFT (real-pair trick); conjugate-symmetry unpack writes both spec rows.
// Raw row stats (shfl reduce -> part[row]). Mean subtraction dropped: the f=0
// bin is fully masked by prop_mask; istd is applied as a per-b scalar in k_img.
__global__ __launch_bounds__(256) void k_fft_time(
        const float* __restrict__ sino, const float* __restrict__ tw,
        const float* __restrict__ apod, float* __restrict__ part,
        float2* __restrict__ spec) {
    __shared__ float2 X[1088];         // 1024 + 64 pad
    __shared__ float sw4[8], qw4[8];
    int tid = threadIdx.x;
    int blk = blockIdx.x;
    int row0 = 2 * blk, row1 = row0 + 1;
    int d0 = row0 & 127;
    float ap0 = apod[d0], ap1 = apod[d0 + 1];
    const float4* p40 = (const float4*)(sino + (size_t)row0 * NT);
    const float4* p41 = (const float4*)(sino + (size_t)row1 * NT);
    const float4* w4 = (const float4*)tw;
    float4 va = p40[tid];
    float4 vb = p41[tid];
    float4 t4 = w4[tid];
    // raw stats over both rows (pre-window)
    float s0 = va.x + va.y + va.z + va.w;
    float q0 = va.x * va.x + va.y * va.y + va.z * va.z + va.w * va.w;
    float s1 = vb.x + vb.y + vb.z + vb.w;
    float q1 = vb.x * vb.x + vb.y * vb.y + vb.z * vb.z + vb.w * vb.w;
#pragma unroll
    for (int off = 32; off > 0; off >>= 1) {
        s0 += __shfl_down(s0, off);
        q0 += __shfl_down(q0, off);
        s1 += __shfl_down(s1, off);
        q1 += __shfl_down(q1, off);
    }
    if ((tid & 63) == 0) {
        int w = tid >> 6;
        sw4[w] = s0; qw4[w] = q0; sw4[4 + w] = s1; qw4[4 + w] = q1;
    }
    // pack: real = row0, imag = row1 (windowed+apodized)
    int t0 = tid * 4;
    X[ax(__brev((unsigned)(t0 + 0)) >> 22)] = make_float2(va.x * t4.x * ap0, vb.x * t4.x * ap1);
    X[ax(__brev((unsigned)(t0 + 1)) >> 22)] = make_float2(va.y * t4.y * ap0, vb.y * t4.y * ap1);
    X[ax(__brev((unsigned)(t0 + 2)) >> 22)] = make_float2(va.z * t4.z * ap0, vb.z * t4.z * ap1);
    X[ax(__brev((unsigned)(t0 + 3)) >> 22)] = make_float2(va.w * t4.w * ap0, vb.w * t4.w * ap1);
    __syncthreads();
    if (tid == 0) {
        part[row0]       = sw4[0] + sw4[1] + sw4[2] + sw4[3];
        part[512 + row0] = qw4[0] + qw4[1] + qw4[2] + qw4[3];
        part[row1]       = sw4[4] + sw4[5] + sw4[6] + sw4[7];
        part[512 + row1] = qw4[4] + qw4[5] + qw4[6] + qw4[7];
    }
    for (int st = 1; st <= 10; ++st) {
        int half = 1 << (st - 1);
        for (int j = tid; j < 512; j += 256) {
            int grp = j >> (st - 1);
            int pos = j & (half - 1);
            int i1 = (grp << st) + pos;
            int i2 = i1 + half;
            float ang = -6.28318530718f * (float)pos / (float)(2 * half);
            float sn, cs; __sincosf(ang, &sn, &cs);
            bfly(X[ax(i1)], X[ax(i2)], cs, sn);
        }
        __syncthreads();
    }
    // unpack: A = (Z[f]+conj(Z[N-f]))/2 (row0), B = (Z[f]-conj(Z[N-f]))/(2i) (row1)
    float2* out0 = spec + (size_t)row0 * NF;
    float2* out1 = spec + (size_t)row1 * NF;
    for (int f = tid; f < NF; f += 256) {
        float2 zf = X[ax(f)];
        float2 zc = X[ax((NT - f) & (NT - 1))];
        out0[f] = make_float2(0.5f * (zf.x + zc.x), 0.5f * (zf.y - zc.y));
        out1[f] = make_float2(0.5f * (zf.y + zc.y), 0.5f * (zc.x - zf.x));
    }
}

// 512 blocks = 4b x 128 f-groups of 4 bins (fg=127 also carries Nyquist f=512).
// 128-pt detector FFT per bin; apply prop_mask*freq_weight.
__global__ __launch_bounds__(256) void k_fft_det(
        const float2* __restrict__ spec, const float* __restrict__ pm,
        const float* __restrict__ fw, float2* __restrict__ wskf) {
    __shared__ float2 Xs[5][128];
    int tid = threadIdx.x;
    int b  = blockIdx.x >> 7;
    int fg = blockIdx.x & 127;
    int rows = (fg == 127) ? 5 : 4;
    int f0 = fg * 4;
    for (int l = tid; l < 512; l += 256) {
        int j = l & 3, dd = l >> 2;
        Xs[j][__brev((unsigned)dd) >> 25] = spec[((size_t)(b * NDET + dd)) * NF + f0 + j];
    }
    if (rows == 5 && tid < 128)
        Xs[4][__brev((unsigned)tid) >> 25] = spec[((size_t)(b * NDET + tid)) * NF + 512];
    __syncthreads();
    for (int st = 1; st <= 7; ++st) {
        int half = 1 << (st - 1);
        for (int l = tid; l < rows * 64; l += 256) {
            int r = l >> 6, qq = l & 63;
            int grp = qq >> (st - 1), pos = qq & (half - 1);
            int i1 = (grp << st) + pos, i2 = i1 + half;
            float ang = -6.28318530718f * (float)pos / (float)(2 * half);
            float sn, cs; __sincosf(ang, &sn, &cs);
            bfly(Xs[r][i1], Xs[r][i2], cs, sn);
        }
        __syncthreads();
    }
    for (int l = tid; l < 512; l += 256) {
        int j = l & 3, k = l >> 2;
        float mw = pm[k * NF + f0 + j] * fw[f0 + j];
        float2 v = Xs[j][k];
        wskf[((size_t)(b * NDET + k)) * NF + f0 + j] = make_float2(v.x * mw, v.y * mw);
    }
    if (rows == 5 && tid < 128) {
        int k = tid;
        float mw = pm[k * NF + 512] * fw[512];
        float2 v = Xs[4][k];
        wskf[((size_t)(b * NDET + k)) * NF + 512] = make_float2(v.x * mw, v.y * mw);
    }
}

// 512 blocks = (p 0..63) x (f-chunk c 0..7). Block p pairs kA=p with kB=128-p
// (shared kz & sincos); block p=0 instead carries kB=64 with its own kz/sincos.
// sk packed per-b as float4 (A.re,A.im,B.re,B.im) -> 4 ds_read_b128 + 1 b64/iter.
// tmpP layout: [c][b][k][y]
__global__ __launch_bounds__(256) void k_prop(const float2* __restrict__ wskf,
                                              float2* __restrict__ tmpP) {
    __shared__ float2 kz2[65];
    __shared__ float4 sk4[4][65];
    int tid = threadIdx.x;
    int p = blockIdx.x >> 3;          // 0..63
    int c = blockIdx.x & 7;           // 0..7
    int f_start = c * 64;
    int nf = (c == 7) ? 65 : 64;
    int kA = p;
    int kB = (p == 0) ? 64 : 128 - p;
    float kxA = (float)p * KX_STEP;
    float kxB = (p == 0) ? 64.0f * KX_STEP : kxA;
    float kxA2 = kxA * kxA, kxB2 = kxB * kxB;
    for (int i = tid; i < nf; i += 256) {
        float oc = (float)(f_start + i) * OC_STEP;
        float o2 = oc * oc;
        float dA = o2 - kxA2, dB = o2 - kxB2;
        kz2[i] = make_float2(dA > 0.f ? sqrtf(dA) : 0.f,
                             dB > 0.f ? sqrtf(dB) : 0.f);
    }
    // stage (coalesced): lane = (bb = tid>>6, i = tid&63)
    {
        int bb = tid >> 6, i = tid & 63;
        float2 vA = wskf[((size_t)(bb * NDET + kA)) * NF + f_start + i];
        float2 vB = wskf[((size_t)(bb * NDET + kB)) * NF + f_start + i];
        sk4[bb][i] = make_float4(vA.x, vA.y, vB.x, vB.y);
        if (c == 7 && tid < 4) {
            float2 wA = wskf[((size_t)(tid * NDET + kA)) * NF + 512];
            float2 wB = wskf[((size_t)(tid * NDET + kB)) * NF + 512];
            sk4[tid][64] = make_float4(wA.x, wA.y, wB.x, wB.y);
        }
    }
    __syncthreads();
    float yp = (float)tid * DY_F;
    float aAr[4] = {0,0,0,0}, aAi[4] = {0,0,0,0};
    float aBr[4] = {0,0,0,0}, aBi[4] = {0,0,0,0};
    bool p0 = (p == 0);
#pragma unroll 4
    for (int i = 0; i < nf; ++i) {
        float2 kz = kz2[i];
        float snA, csA; __sincosf(yp * kz.x, &snA, &csA);
        float snB, csB;
        if (p0) { __sincosf(yp * kz.y, &snB, &csB); }
        else    { snB = snA; csB = csA; }
#pragma unroll
        for (int bb = 0; bb < 4; ++bb) {
            float4 v = sk4[bb][i];
            aAr[bb] += v.x * csA - v.y * snA;  aAi[bb] += v.x * snA + v.y * csA;
            aBr[bb] += v.z * csB - v.w * snB;  aBi[bb] += v.z * snB + v.w * csB;
        }
    }
    int y = tid;
    size_t cb = (size_t)c * NB * NDET;
#pragma unroll
    for (int bb = 0; bb < 4; ++bb) {
        tmpP[(cb + bb * NDET + kA) * NYI + y] = make_float2(aAr[bb], aAi[bb]);
        tmpP[(cb + bb * NDET + kB) * NYI + y] = make_float2(aBr[bb], aBi[bb]);
    }
}

// img[b,y,x] = istd[b]/131072 * Re sum_k tmp[b,y,k] * e^{i kx[k] * x * dx}
// 512 blocks = (y, b-half). ts packed float4 (b0.re,b0.im,b1.re,b1.im) per k;
// rotation recurrence: 1 sincos/thread, k/-k paired, 2 ds_read_b128/iter.
__global__ __launch_bounds__(256) void k_img(const float2* __restrict__ tmpP,
                                             const float* __restrict__ part,
                                             float* __restrict__ outp) {
    __shared__ float4 ts4[128];
    __shared__ float sred[4];
    int tid = threadIdx.x;
    int y  = blockIdx.x >> 1;
    int bh = blockIdx.x & 1;          // b in {2bh, 2bh+1}
    // fold per-row stats partials: g = (local b)*2 + (0:sum,1:sumsq), one wave per g
    {
        int g = tid >> 6, lane = tid & 63;
        int bb = 2 * bh + (g >> 1);
        int which = g & 1;
        float v = part[which * 512 + bb * 128 + lane] +
                  part[which * 512 + bb * 128 + 64 + lane];
#pragma unroll
        for (int off = 32; off > 0; off >>= 1) v += __shfl_down(v, off);
        if (lane == 0) sred[g] = v;
    }
    // fold tmpP chunks
    int bl = tid >> 7;                // 0..1
    int k  = tid & 127;
    float2 a = make_float2(0.f, 0.f);
#pragma unroll
    for (int cc = 0; cc < NCH; ++cc) {
        float2 v = tmpP[(((size_t)cc * NB + 2 * bh + bl) * NDET + k) * NYI + y];
        a.x += v.x; a.y += v.y;
    }
    {
        float* tf = (float*)&ts4[k];
        tf[2 * bl + 0] = a.x;
        tf[2 * bl + 1] = a.y;
    }
    __syncthreads();
    const float inv_n = 1.0f / 131072.0f;
    float m0 = sred[0] * inv_n;
    float v0 = sred[1] * inv_n - m0 * m0;
    float m1 = sred[2] * inv_n;
    float v1 = sred[3] * inv_n - m1 * m1;
    // scale = istd[b] / (n_det * sum(freq_weight)) = istd[b] / 131072
    float sc0 = inv_n / sqrtf(v0 + 1.1920929e-7f);
    float sc1 = inv_n / sqrtf(v1 + 1.1920929e-7f);
    float alpha = KX_STEP * (float)tid * DX_F;
    float sa, ca; __sincosf(alpha, &sa, &ca);
    float4 t0v = ts4[0];
    float acc0 = t0v.x, acc1 = t0v.z;             // p=0: cos=1, sin=0
    float c = ca, s = sa;
    for (int p = 1; p <= 63; ++p) {
        float4 tp = ts4[p], tm = ts4[128 - p];
        acc0 += c * (tp.x + tm.x) - s * (tp.y - tm.y);
        acc1 += c * (tp.z + tm.z) - s * (tp.w - tm.w);
        float nc = c * ca - s * sa;
        s = s * ca + c * sa;
        c = nc;
    }
    // p=64 (kk=-64): cos=c, sin=-s
    float4 t64 = ts4[64];
    acc0 += c * t64.x + s * t64.y;
    acc1 += c * t64.z + s * t64.w;
    outp[((size_t)(2 * bh + 0) * NYI + y) * NXI + tid] = acc0 * sc0;
    outp[((size_t)(2 * bh + 1) * NYI + y) * NXI + tid] = acc1 * sc1;
}

extern "C" void kernel_launch(void* const* d_in, const int* in_sizes, int n_in,
                              void* d_out, int out_size, void* d_ws, size_t ws_size,
                              hipStream_t stream) {
    const float* sino = (const float*)d_in[0];
    const float* tw   = (const float*)d_in[1];
    const float* apod = (const float*)d_in[2];
    const float* fw   = (const float*)d_in[3];
    const float* pm   = (const float*)d_in[4];
    // d_in[5] (phase_x) and d_in[6] (phase_y) are recomputed on the fly.

    float*  wsf   = (float*)d_ws;
    float*  part  = wsf;                          // 1024 floats (512 sum + 512 sumsq)
    float2* spec  = (float2*)(wsf + 1024);        // [4][128][513]
    float2* wskf  = spec + (size_t)NB * NDET * NF;  // [4][128][513]
    float2* tmpP  = wskf + (size_t)NB * NDET * NF;  // [8c][4b][128k][256y]
    float*  outp  = (float*)d_out;

    k_fft_time<<<dim3(256), dim3(256), 0, stream>>>(sino, tw, apod, part, spec);
    k_fft_det <<<dim3(512), dim3(256), 0, stream>>>(spec, pm, fw, wskf);
    k_prop    <<<dim3(512), dim3(256), 0, stream>>>(wskf, tmpP);
    k_img     <<<dim3(512), dim3(256), 0, stream>>>(tmpP, part, outp);
}